// Round 1
// baseline (765.654 us; speedup 1.0000x reference)
//
#include <hip/hip_runtime.h>
#include <math.h>

// RNN_197568496340: 6-layer ReLU RNN (T=1024,B=2048,IN=2,H=20) + FC(20->2) + log_softmax.
//
// R6: attack the 2x VALU-instruction inflation + exposed LDS latency seen in R5
// (568us, VALUBusy 59%, VGPR_Count=64 -> weights AGPR-parked, ~390 VALU/step-pair
// vs ~220 expected):
//  - amdgpu_waves_per_eu(2,2): grid supplies only 8 blocks/CU (=2 waves/EU), so tell
//    the allocator that's the target -> 256-VGPR budget -> 80 weight floats live in
//    arch VGPRs, no accvgpr churn. (R5's launch_bounds(64,2) was only a FLOOR; the
//    occupancy heuristic still shrank to 64 VGPRs chasing unreachable 8 waves/EU.)
//  - v_pk_fma_f32 via __builtin_elementwise_fma on float2: 80 -> 40 FMA issue slots.
//  - software pipeline: FMA -> LDS writes -> issue next-step ds_reads -> epilogue
//    (head softmax/store, x prefetch) in the read shadow. sched_barrier(0) pins the
//    reads before the epilogue.
//  - steady/edge loop split: steps 6..1019 run guard-free (no per-step v_cmp/exec
//    churn); incremental pointers replace per-step 64-bit address muls.

#define TT 1024
#define BB 2048
#define HH 20
#define LL 6
#define SLOTW 40
#define BUFW  (8 * SLOTW)       // 320 words/parity: slots 0=x,1..6=layer outs,7=zeros
#define NSTEPS (TT + LL)        // 1030 (even)

// ws layout (floats)
#define WS_WI   0               // padded Wih: [6][20][20] (layer0 = Wih0 zero-padded)
#define WS_BIAS 2400            // BiasTab: [61][2]  (role 60 = fcb)

typedef float v2f __attribute__((ext_vector_type(2)));

#if defined(__has_builtin)
#  if __has_builtin(__builtin_elementwise_fma)
#    define PKFMA(a, b, c) __builtin_elementwise_fma((a), (b), (c))
#  endif
#endif
#ifndef PKFMA
__device__ inline v2f pkfma_fallback(v2f a, v2f b, v2f c) {
    return v2f{fmaf(a.x, b.x, c.x), fmaf(a.y, b.y, c.y)};
}
#  define PKFMA(a, b, c) pkfma_fallback((a), (b), (c))
#endif

struct SteadyT { static constexpr bool value = true;  };
struct EdgeT   { static constexpr bool value = false; };

__global__ void stage_ws(const float* __restrict__ Wih0,
                         const float* __restrict__ Wih,
                         const float* __restrict__ bih,
                         const float* __restrict__ bhh,
                         const float* __restrict__ fcb,
                         float* __restrict__ ws) {
    const int i = threadIdx.x + blockIdx.x * blockDim.x;
    if (i < 2400) {
        const int l = i / 400, r = i % 400, j = r / 20, k = r % 20;
        float v;
        if (l == 0) v = (k < 2) ? Wih0[j * 2 + k] : 0.f;
        else        v = Wih[(l - 1) * 400 + r];
        ws[WS_WI + i] = v;
    }
    if (i < 122) {
        const int role = i >> 1, c = i & 1;
        float v;
        if (role < 60) {
            const int l = role / 10, j = 2 * (role % 10) + c;
            v = bih[l * HH + j] + bhh[l * HH + j];
        } else {
            v = fcb[c];
        }
        ws[WS_BIAS + i] = v;
    }
}

__global__ __attribute__((amdgpu_flat_work_group_size(64, 64), amdgpu_waves_per_eu(2, 2)))
void rnn_fused(const float* __restrict__ x,      // [1024][2048][2]
               const float* __restrict__ Whh,    // [6][20][20]
               const float* __restrict__ fcw,    // [2][20]
               const float* __restrict__ ws,     // staged WI_pad + BiasTab
               float* __restrict__ out)          // [1024][2048][2]
{
    __shared__ __align__(16) float As[2 * BUFW];   // 2560 B

    const int lane = threadIdx.x;
    // XCD swizzle: consecutive b on the same XCD -> L2 write combining
    const int b = ((blockIdx.x & 7) << 8) | (blockIdx.x >> 3);

    const int  role = (lane < 60) ? lane : 60;
    const int  l    = role / 10;            // 0..6 (6 = head pseudo-layer)
    const int  j    = 2 * (role % 10);      // 0 for head
    const bool head = (role == 60);

    // ---- branch-free uniform weight init (pointers differ, code identical) ----
    const float4* pwh = (const float4*)(head ? Whh : (Whh + (l * HH + j) * HH));
    const float4* pwi = (const float4*)(head ? fcw : (ws + WS_WI + (l * HH + j) * HH));
    const float2  bt  = *(const float2*)(ws + WS_BIAS + 2 * role);

    // weights as float2 pairs: wh[0..9]=row j, wh[10..19]=row j+1 (rows contiguous)
    v2f wh[20], wi[20];
#pragma unroll
    for (int q = 0; q < 10; ++q) {
        const float4 th = pwh[q], ti = pwi[q];
        wh[2 * q]     = v2f{th.x, th.y};
        wh[2 * q + 1] = v2f{th.z, th.w};
        wi[2 * q]     = v2f{ti.x, ti.y};
        wi[2 * q + 1] = v2f{ti.z, ti.w};
    }

    // ---- LDS init: everything zero (h(-1)=0, zero-slot stays zero forever) ----
    for (int i = lane; i < 2 * BUFW; i += 64) As[i] = 0.f;

    // x staging: x[0] -> buf0 slot0; ring lanes 61..63 hold x[1..3]
    const float2* xp = (const float2*)x;
    float2 xh = make_float2(0.f, 0.f);
    if (lane == 61) *(float2*)&As[0] = xp[b];
    if (lane >= 61) xh = xp[(size_t)(lane - 60) * BB + b];

    // per-lane LDS word offsets (uniform formula, head included)
    const int ioff = l * SLOTW;             // input slot (head: slot 6 = h5)
    const int hoff = (l + 1) * SLOTW;       // recurrent slot (head: slot 7 = zeros)

    // incremental global pointers (no per-step 64-bit muls)
    float2*       oph  = (float2*)out + b;                         // head cursor t=0
    const float2* xq   = xp + (size_t)(lane - 60 + 3) * BB + b;    // ring: t = d+4
    const float2* xend = xp + (size_t)(TT - 1) * BB + b;

    // pipeline registers: operands for the *next* step
    float4 ch[5], ci[5];
    auto ldops = [&](const float* rb) {
        const float4* hp = (const float4*)(rb + hoff);
        const float4* ip = (const float4*)(rb + ioff);
#pragma unroll
        for (int q = 0; q < 5; ++q) { ch[q] = hp[q]; ci[q] = ip[q]; }
    };
    ldops(As);   // step-0 operands (after zero init + x0 publish; per-wave in-order)

    float* const buf0 = As;
    float* const buf1 = As + BUFW;

    auto body = [&](int s, float* wb, auto steadyc) {
        constexpr bool STEADY = decltype(steadyc)::value;

        // ---- FMA phase: 40x v_pk_fma_f32, 4 independent chains ----
        v2f ah0 = v2f{0.f, 0.f},  ah1 = v2f{0.f, 0.f};
        v2f ai0 = v2f{bt.x, 0.f}, ai1 = v2f{bt.y, 0.f};
#pragma unroll
        for (int q = 0; q < 5; ++q) {
            const v2f hlo = v2f{ch[q].x, ch[q].y}, hhi = v2f{ch[q].z, ch[q].w};
            const v2f ilo = v2f{ci[q].x, ci[q].y}, ihi = v2f{ci[q].z, ci[q].w};
            ah0 = PKFMA(wh[2 * q],      hlo, ah0);
            ah0 = PKFMA(wh[2 * q + 1],  hhi, ah0);
            ah1 = PKFMA(wh[10 + 2 * q],     hlo, ah1);
            ah1 = PKFMA(wh[10 + 2 * q + 1], hhi, ah1);
            ai0 = PKFMA(wi[2 * q],      ilo, ai0);
            ai0 = PKFMA(wi[2 * q + 1],  ihi, ai0);
            ai1 = PKFMA(wi[10 + 2 * q],     ilo, ai1);
            ai1 = PKFMA(wi[10 + 2 * q + 1], ihi, ai1);
        }
        const v2f t0 = ah0 + ai0;
        const v2f t1 = ah1 + ai1;
        const float a0 = t0.x + t0.y;
        const float a1 = t1.x + t1.y;

        // ---- write phase (must precede next-step reads; per-wave in-order LDS) ----
        if (role < 60) {
            if (STEADY || (unsigned)(s - l) < TT) {                // t in [0,1023]
                float2 r;
                r.x = fmaxf(a0, 0.f);
                r.y = fmaxf(a1, 0.f);
                *(float2*)(wb + hoff + j) = r;
            }
        } else if (lane >= 61 && (lane - 61) == (s % 3)) {
            if (STEADY || s + 1 < TT) *(float2*)wb = xh;           // publish x[s+1]
        }

        // ---- issue next-step reads from the buffer just written ----
        ldops(wb);
        __builtin_amdgcn_sched_barrier(0);   // pin read issue before the epilogue

        // ---- epilogue hidden in the LDS-read shadow ----
        if (lane == 60) {
            if (STEADY || s >= LL) {
                const float mx  = fmaxf(a0, a1);
                const float lse = mx + __logf(__expf(a0 - mx) + __expf(a1 - mx));
                *oph = make_float2(a0 - lse, a1 - lse);
                oph += BB;
            }
        } else if (lane >= 61 && (lane - 61) == (s % 3)) {
            if (STEADY) {                      // steady guarantees t = s+4 <= 1023
                xh = *xq;
                xq += 3 * (size_t)BB;
            } else {
                if (xq <= xend) xh = *xq;      // edge: clamp, never OOB
                xq += 3 * (size_t)BB;
            }
        }
    };

    // edge: s in [0,6) and [1020,1030); steady: [6,1020) -> all guards fold away
    for (int s = 0; s < 6; s += 2)          { body(s, buf1, EdgeT{});   body(s + 1, buf0, EdgeT{});   }
    for (int s = 6; s < 1020; s += 2)       { body(s, buf1, SteadyT{}); body(s + 1, buf0, SteadyT{}); }
    for (int s = 1020; s < NSTEPS; s += 2)  { body(s, buf1, EdgeT{});   body(s + 1, buf0, EdgeT{});   }
}

extern "C" void kernel_launch(void* const* d_in, const int* in_sizes, int n_in,
                              void* d_out, int out_size, void* d_ws, size_t ws_size,
                              hipStream_t stream) {
    const float* x    = (const float*)d_in[0];
    const float* Wih0 = (const float*)d_in[1];
    const float* Wih  = (const float*)d_in[2];
    const float* Whh  = (const float*)d_in[3];
    const float* bih  = (const float*)d_in[4];
    const float* bhh  = (const float*)d_in[5];
    const float* fcw  = (const float*)d_in[6];
    const float* fcb  = (const float*)d_in[7];
    float* out = (float*)d_out;
    float* ws  = (float*)d_ws;

    stage_ws<<<dim3(3), dim3(1024), 0, stream>>>(Wih0, Wih, bih, bhh, fcb, ws);
    rnn_fused<<<dim3(BB), dim3(64), 0, stream>>>(x, Whh, fcw, ws, out);
}

// Round 2
// 715.562 us; speedup vs baseline: 1.0700x; 1.0700x over previous
//
#include <hip/hip_runtime.h>
#include <math.h>

// RNN_197568496340: 6-layer ReLU RNN (T=1024,B=2048,IN=2,H=20) + FC(20->2) + log_softmax.
//
// R7: structural fix for the register-pressure wall seen in R5/R6.
// R5 (568us): 1 wave/batch -> 80 weight floats/lane can't live in arch VGPRs
// (VGPR_Count=64, ~80 accvgpr moves/step, VALUBusy 59% on 2x inflated stream).
// R6 (766us): tried to raise the allocator budget in-place; allocator gave 88
// VGPRs + scratch churn instead. Lesson: pressure is structural.
//
// R7 decomposition: 2 waves/batch, ONE output row per lane.
//  - 128 threads: wave0 = layers 0..2 (tid 0..59) + x-ring (61..63);
//    wave1 = layers 3..5 (tid 64..123) + head pair (124,125).
//  - per-lane weights: 1 Whh row + 1 Wih row = 40 floats -> total live ~100
//    regs, fits under amdgpu_waves_per_eu(4,4)'s 128-VGPR cap. No AGPR parking.
//  - occupancy doubles to 4 waves/SIMD (grid 2048 x 2 waves / 256 CU).
//  - LDS reads are 20-lane same-address broadcasts; 3-layer-per-wave split puts
//    slots on disjoint bank groups -> bank conflicts ~0.
//  - diagonal layer schedule kept (layer l computes t=s-l at step s); slot 7
//    stays all-zero = head's recurrent operand (exact 0 contribution).
//  - cost: one __syncthreads per step for the cross-wave handoffs.

#define TT 1024
#define BB 2048
#define HH 20
#define LL 6
#define SLOTW 40
#define BUFW  (8 * SLOTW)       // 320 words/parity: slots 0=x,1..6=layer outs,7=zeros
#define NSTEPS (TT + LL)        // 1030 (even)

// ws layout (floats)
#define WS_WI   0               // padded Wih: [6][20][20] (layer0 = Wih0 zero-padded)
#define WS_BIAS 2400            // BiasTab: [122]  (roles 0..119 = l*20+j, 120/121 = fcb)

__global__ void stage_ws(const float* __restrict__ Wih0,
                         const float* __restrict__ Wih,
                         const float* __restrict__ bih,
                         const float* __restrict__ bhh,
                         const float* __restrict__ fcb,
                         float* __restrict__ ws) {
    const int i = threadIdx.x + blockIdx.x * blockDim.x;
    if (i < 2400) {
        const int l = i / 400, r = i % 400, j = r / 20, k = r % 20;
        float v;
        if (l == 0) v = (k < 2) ? Wih0[j * 2 + k] : 0.f;
        else        v = Wih[(l - 1) * 400 + r];
        ws[WS_WI + i] = v;
    }
    if (i < 122) {
        float v;
        if (i < 120) v = bih[i] + bhh[i];    // bih/bhh are [6][20] row-major
        else         v = fcb[i - 120];
        ws[WS_BIAS + i] = v;
    }
}

__global__ __attribute__((amdgpu_flat_work_group_size(128, 128), amdgpu_waves_per_eu(4, 4)))
void rnn_fused(const float* __restrict__ x,      // [1024][2048][2]
               const float* __restrict__ Whh,    // [6][20][20]
               const float* __restrict__ fcw,    // [2][20]
               const float* __restrict__ ws,     // staged WI_pad + BiasTab
               float* __restrict__ out)          // [1024][2048][2]
{
    __shared__ __align__(16) float As[2 * BUFW];   // 2560 B

    const int tid = threadIdx.x;
    // XCD swizzle: consecutive b on the same XCD -> L2 locality for x reads/out writes
    const int b = ((blockIdx.x & 7) << 8) | (blockIdx.x >> 3);

    // ---- role mapping ----
    const bool w1        = tid >= 64;
    const int  lt        = w1 ? tid - 64 : tid;        // lane-in-wave
    const bool layerLane = lt < 60;
    const int  l         = lt / 20 + (w1 ? 3 : 0);     // 0..5 for layer lanes
    const int  j         = lt % 20;
    const bool headLane  = w1 && (lt == 60 || lt == 61);   // tid 124,125
    const int  hc        = lt - 60;                    // head channel 0/1
    const bool ringLane  = !w1 && lt >= 61;            // tid 61..63
    const int  rd        = lt - 61;                    // ring phase 0..2
    const bool comp      = layerLane || headLane;

    // uniform dot-product parameters (head: input=slot6(h5), recurrent=slot7(zeros))
    const int ioff  = headLane ? 6 * SLOTW : l * SLOTW;
    const int hoff  = headLane ? 7 * SLOTW : (l + 1) * SLOTW;
    const int brole = headLane ? 120 + hc : (layerLane ? l * HH + j : 0);

    const float4* pwh = (const float4*)(Whh + (layerLane ? (l * HH + j) * HH : 0));
    const float4* pwi = headLane ? (const float4*)(fcw + hc * HH)
                                 : (const float4*)(ws + WS_WI + (layerLane ? (l * HH + j) * HH : 0));
    const float bias = ws[WS_BIAS + brole];

    float4 wh[5], wi[5];   // 40 floats/lane: one Whh row + one Wih row
#pragma unroll
    for (int q = 0; q < 5; ++q) { wh[q] = pwh[q]; wi[q] = pwi[q]; }

    // ---- LDS init: all zero (h(-1)=0; slot 7 stays zero forever) ----
    for (int i = tid; i < 2 * BUFW; i += 128) As[i] = 0.f;

    // x staging (wave0 lanes, after wave0's zero stores in program order):
    const float2* xp = (const float2*)x;
    float2 xh = make_float2(0.f, 0.f);
    if (tid == 61) *(float2*)&As[0] = xp[b];                       // x[0] -> buf0 slot0
    if (ringLane)  xh = xp[(size_t)(rd + 1) * BB + b];             // hold x[1..3]

    // incremental global cursors
    float2*       oph  = (float2*)out + b;                         // head out, t=0
    const float2* xq   = xp + (size_t)(rd + 4) * BB + b;           // next prefetch t=s+4
    const float2* xend = xp + (size_t)(TT - 1) * BB + b;

    __syncthreads();   // zero-init + x[0] visible to both waves

    float* const buf0 = As;
    float* const buf1 = As + BUFW;

    auto step = [&](int s, const float* rb, float* wb) {
        float a = 0.f;
        if (comp) {
            const float4* hp = (const float4*)(rb + hoff);
            const float4* ip = (const float4*)(rb + ioff);
            float4 ch[5], ci[5];
#pragma unroll
            for (int q = 0; q < 5; ++q) { ch[q] = hp[q]; ci[q] = ip[q]; }
            float ah = 0.f, ai = bias;
#pragma unroll
            for (int q = 0; q < 5; ++q) {
                ah = fmaf(wh[q].x, ch[q].x, ah); ah = fmaf(wh[q].y, ch[q].y, ah);
                ah = fmaf(wh[q].z, ch[q].z, ah); ah = fmaf(wh[q].w, ch[q].w, ah);
                ai = fmaf(wi[q].x, ci[q].x, ai); ai = fmaf(wi[q].y, ci[q].y, ai);
                ai = fmaf(wi[q].z, ci[q].z, ai); ai = fmaf(wi[q].w, ci[q].w, ai);
            }
            a = ah + ai;
        }

        // ---- LDS publishes for step s+1 ----
        if (layerLane) {
            if ((unsigned)(s - l) < TT) wb[hoff + j] = fmaxf(a, 0.f);   // t valid
        } else if (ringLane && rd == (s % 3)) {
            if (s + 1 < TT) *(float2*)wb = xh;                          // publish x[s+1]
        }

        // ---- epilogues (hidden before the barrier) ----
        if (headLane) {
            const float po = __shfl_xor(a, 1, 64);   // partner channel, lanes 124<->125
            if (s >= LL) {
                const float a0 = hc ? po : a;
                const float a1 = hc ? a : po;
                const float mx  = fmaxf(a0, a1);
                const float lse = mx + __logf(__expf(a0 - mx) + __expf(a1 - mx));
                if (hc == 0) { *oph = make_float2(a0 - lse, a1 - lse); oph += BB; }
            }
        } else if (ringLane && rd == (s % 3)) {
            if (xq <= xend) xh = *xq;                // clamped prefetch x[s+4]
            xq += 3 * (size_t)BB;
        }

        __syncthreads();   // cross-wave handoff (lgkm drain + barrier)
    };

    for (int s = 0; s < NSTEPS; s += 2) {
        step(s,     buf0, buf1);
        step(s + 1, buf1, buf0);
    }
}

extern "C" void kernel_launch(void* const* d_in, const int* in_sizes, int n_in,
                              void* d_out, int out_size, void* d_ws, size_t ws_size,
                              hipStream_t stream) {
    const float* x    = (const float*)d_in[0];
    const float* Wih0 = (const float*)d_in[1];
    const float* Wih  = (const float*)d_in[2];
    const float* Whh  = (const float*)d_in[3];
    const float* bih  = (const float*)d_in[4];
    const float* bhh  = (const float*)d_in[5];
    const float* fcw  = (const float*)d_in[6];
    const float* fcb  = (const float*)d_in[7];
    float* out = (float*)d_out;
    float* ws  = (float*)d_ws;

    stage_ws<<<dim3(3), dim3(1024), 0, stream>>>(Wih0, Wih, bih, bhh, fcb, ws);
    rnn_fused<<<dim3(BB), dim3(128), 0, stream>>>(x, Whh, fcw, ws, out);
}

// Round 6
// 426.700 us; speedup vs baseline: 1.7944x; 1.6770x over previous
//
#include <hip/hip_runtime.h>
#include <math.h>

// RNN_197568496340: 6-layer ReLU RNN (T=1024,B=2048,IN=2,H=20) + FC(20->2) + log_softmax.
//
// R11: revert to the R5 568us PASSING structure (2048 single-wave blocks, diagonal
// layer schedule, double-buffered 8-slot LDS, zero barriers) after R9/R10's new
// ring schedule failed deterministically (identical absmax with and without the asm
// pin -> logic bug in that schedule, abandoned). Apply only deltas individually
// validated in passing runs:
//  - deferred softmax: head lane stores raw logits; logsm pass (~12us) applies
//    log_softmax in place. Removes log/exp/lse from the 1030-step hot loop.
//  - steady/edge split (R6-validated): s in [6,1020) runs guard-free.
//  - 6-step unroll: s%3 ring phase + buffer parity become compile-time; incremental
//    oph/xq pointers replace per-step 64-bit address math.
//  - amdgpu_waves_per_eu(2,2): grid gives exactly 2 waves/EU; raise the register
//    budget so the 80 weight floats/lane can live in arch VGPRs (diagnostic:
//    VGPR_Count > 96 means the R5-era AGPR parking is gone).

#define TT 1024
#define BB 2048
#define HH 20
#define LL 6
#define SLOTW 40
#define BUFW  (8 * SLOTW)       // 320 words/parity: slots 0=x,1..6=layer outs,7=zeros
#define NSTEPS (TT + LL)        // 1030 (even)

// ws layout (floats)
#define WS_WI   0               // padded Wih: [6][20][20] (layer0 = Wih0 zero-padded)
#define WS_BIAS 2400            // BiasTab: [61][2]  (role 60 = fcb)

struct SteadyT { static constexpr bool value = true;  };
struct EdgeT   { static constexpr bool value = false; };

__global__ void stage_ws(const float* __restrict__ Wih0,
                         const float* __restrict__ Wih,
                         const float* __restrict__ bih,
                         const float* __restrict__ bhh,
                         const float* __restrict__ fcb,
                         float* __restrict__ ws) {
    const int i = threadIdx.x + blockIdx.x * blockDim.x;
    if (i < 2400) {
        const int l = i / 400, r = i % 400, j = r / 20, k = r % 20;
        float v;
        if (l == 0) v = (k < 2) ? Wih0[j * 2 + k] : 0.f;
        else        v = Wih[(l - 1) * 400 + r];
        ws[WS_WI + i] = v;
    }
    if (i < 122) {
        const int role = i >> 1, c = i & 1;
        float v;
        if (role < 60) {
            const int l = role / 10, j = 2 * (role % 10) + c;
            v = bih[l * HH + j] + bhh[l * HH + j];
        } else {
            v = fcb[c];
        }
        ws[WS_BIAS + i] = v;
    }
}

__global__ void logsm(float* __restrict__ o) {
    const size_t n = (size_t)TT * BB;            // float2 elements
    float2* p = (float2*)o;
    for (size_t idx = (size_t)blockIdx.x * blockDim.x + threadIdx.x; idx < n;
         idx += (size_t)gridDim.x * blockDim.x) {
        float2 v = p[idx];
        const float mx  = fmaxf(v.x, v.y);
        const float lse = mx + __logf(__expf(v.x - mx) + __expf(v.y - mx));
        p[idx] = make_float2(v.x - lse, v.y - lse);
    }
}

__global__ __attribute__((amdgpu_flat_work_group_size(64, 64), amdgpu_waves_per_eu(2, 2)))
void rnn_fused(const float* __restrict__ x,      // [1024][2048][2]
               const float* __restrict__ Whh,    // [6][20][20]
               const float* __restrict__ fcw,    // [2][20]
               const float* __restrict__ ws,     // staged WI_pad + BiasTab
               float* __restrict__ out)          // [1024][2048][2] (raw logits here)
{
    __shared__ __align__(16) float As[2 * BUFW];   // 2560 B

    const int lane = threadIdx.x;
    // XCD swizzle: consecutive b on the same XCD -> L2 locality
    const int b = ((blockIdx.x & 7) << 8) | (blockIdx.x >> 3);

    const int  role = (lane < 60) ? lane : 60;
    const int  l    = role / 10;            // 0..6 (6 = head pseudo-layer)
    const int  j    = 2 * (role % 10);      // 0 for head
    const bool head = (role == 60);

    // ---- branch-free uniform weight init (pointers differ, code identical) ----
    const float4* pwh = (const float4*)(head ? Whh : (Whh + (l * HH + j) * HH));
    const float4* pwi = (const float4*)(head ? fcw : (ws + WS_WI + (l * HH + j) * HH));
    const float2  bt  = *(const float2*)(ws + WS_BIAS + 2 * role);

    float4 whA[5], whB[5], wiA[5], wiB[5];
#pragma unroll
    for (int q = 0; q < 5; ++q) {
        whA[q] = pwh[q];
        whB[q] = pwh[5 + q];
        wiA[q] = pwi[q];
        wiB[q] = pwi[5 + q];
    }

    // ---- LDS init: everything zero (h(-1)=0, zero-slot stays zero forever) ----
    for (int i = lane; i < 2 * BUFW; i += 64) As[i] = 0.f;

    // x staging: x[0] -> buf0 slot0; ring lanes 61..63 hold x[1..3]
    const float2* xp = (const float2*)x;
    float2 xh = make_float2(0.f, 0.f);
    if (lane == 61) *(float2*)&As[0] = xp[b];
    if (lane >= 61) xh = xp[(size_t)(lane - 60) * BB + b];

    // per-lane LDS word offsets (uniform formula, head included)
    const int ioff = l * SLOTW;             // input slot (head: slot 6 = h5)
    const int hoff = (l + 1) * SLOTW;       // recurrent slot (head: slot 7 = zeros)

    // incremental global cursors
    const int rdc = (lane >= 61) ? (lane - 61) : 0;                 // ring phase 0..2
    float2*       oph  = (float2*)out + b - (ptrdiff_t)LL * BB;     // head cursor, t=s-6
    const float2* xq   = xp + (size_t)(rdc + 4) * BB + b;           // prefetch target x[s+4]
    const float2* xend = xp + (size_t)(TT - 1) * BB + b;

    auto step = [&](int s, int ph, const float* rb, float* wb, auto sc) {
        constexpr bool STEADY = decltype(sc)::value;
        const float4* hp = (const float4*)(rb + hoff);
        const float4* ip = (const float4*)(rb + ioff);

        float ah0 = 0.f, ah1 = 0.f;
        float ai0 = bt.x, ai1 = bt.y;
#pragma unroll
        for (int q = 0; q < 5; ++q) {
            const float4 h4 = hp[q];
            const float4 i4 = ip[q];
            ah0 = fmaf(whA[q].x, h4.x, ah0); ah0 = fmaf(whA[q].y, h4.y, ah0);
            ah0 = fmaf(whA[q].z, h4.z, ah0); ah0 = fmaf(whA[q].w, h4.w, ah0);
            ah1 = fmaf(whB[q].x, h4.x, ah1); ah1 = fmaf(whB[q].y, h4.y, ah1);
            ah1 = fmaf(whB[q].z, h4.z, ah1); ah1 = fmaf(whB[q].w, h4.w, ah1);
            ai0 = fmaf(wiA[q].x, i4.x, ai0); ai0 = fmaf(wiA[q].y, i4.y, ai0);
            ai0 = fmaf(wiA[q].z, i4.z, ai0); ai0 = fmaf(wiA[q].w, i4.w, ai0);
            ai1 = fmaf(wiB[q].x, i4.x, ai1); ai1 = fmaf(wiB[q].y, i4.y, ai1);
            ai1 = fmaf(wiB[q].z, i4.z, ai1); ai1 = fmaf(wiB[q].w, i4.w, ai1);
        }
        const float a0 = ah0 + ai0;
        const float a1 = ah1 + ai1;

        if (role < 60) {
            if (STEADY || (unsigned)(s - l) < TT) {                  // t in [0,1023]
                float2 r;
                r.x = fmaxf(a0, 0.f);
                r.y = fmaxf(a1, 0.f);
                *(float2*)(wb + hoff + j) = r;
            }
        } else if (lane == 60) {
            if (STEADY || s >= LL) *oph = make_float2(a0, a1);       // raw logits
            oph += BB;
        } else {
            // x ring: lane rdc publishes x[s+1] when ph==rdc, then prefetches x[s+4]
            if (rdc == ph) {
                if (STEADY || s + 1 < TT) *(float2*)wb = xh;
                if (STEADY)              xh = *xq;                   // s+4 <= 1023 here
                else if (xq <= xend)     xh = *xq;
                xq += 3 * (size_t)BB;
            }
        }
        __builtin_amdgcn_sched_barrier(0);   // scheduling fence only
    };

    float* const buf0 = As;
    float* const buf1 = As + BUFW;

    // ---- edge pre: s = 0..5 (ph = s%3, buffers alternate from buf0->buf1) ----
    step(0, 0, buf0, buf1, EdgeT{}); step(1, 1, buf1, buf0, EdgeT{});
    step(2, 2, buf0, buf1, EdgeT{}); step(3, 0, buf1, buf0, EdgeT{});
    step(4, 1, buf0, buf1, EdgeT{}); step(5, 2, buf1, buf0, EdgeT{});

    // ---- steady: s in [6,1020), 169 x 6 steps, all guards folded, s unused ----
#pragma unroll 1
    for (int it = 0; it < 169; ++it) {
        step(0, 0, buf0, buf1, SteadyT{}); step(0, 1, buf1, buf0, SteadyT{});
        step(0, 2, buf0, buf1, SteadyT{}); step(0, 0, buf1, buf0, SteadyT{});
        step(0, 1, buf0, buf1, SteadyT{}); step(0, 2, buf1, buf0, SteadyT{});
    }

    // ---- edge post: s = 1020..1029 (1020%3 == 0) ----
    step(1020, 0, buf0, buf1, EdgeT{}); step(1021, 1, buf1, buf0, EdgeT{});
    step(1022, 2, buf0, buf1, EdgeT{}); step(1023, 0, buf1, buf0, EdgeT{});
    step(1024, 1, buf0, buf1, EdgeT{}); step(1025, 2, buf1, buf0, EdgeT{});
    step(1026, 0, buf0, buf1, EdgeT{}); step(1027, 1, buf1, buf0, EdgeT{});
    step(1028, 2, buf0, buf1, EdgeT{}); step(1029, 0, buf1, buf0, EdgeT{});
}

extern "C" void kernel_launch(void* const* d_in, const int* in_sizes, int n_in,
                              void* d_out, int out_size, void* d_ws, size_t ws_size,
                              hipStream_t stream) {
    const float* x    = (const float*)d_in[0];
    const float* Wih0 = (const float*)d_in[1];
    const float* Wih  = (const float*)d_in[2];
    const float* Whh  = (const float*)d_in[3];
    const float* bih  = (const float*)d_in[4];
    const float* bhh  = (const float*)d_in[5];
    const float* fcw  = (const float*)d_in[6];
    const float* fcb  = (const float*)d_in[7];
    float* out = (float*)d_out;
    float* ws  = (float*)d_ws;

    stage_ws<<<dim3(3), dim3(1024), 0, stream>>>(Wih0, Wih, bih, bhh, fcb, ws);
    rnn_fused<<<dim3(BB), dim3(64), 0, stream>>>(x, Whh, fcw, ws, out);
    logsm<<<dim3(2048), dim3(256), 0, stream>>>(out);
}